// Round 5
// baseline (97.566 us; speedup 1.0000x reference)
//
#include <hip/hip_runtime.h>

#define DIM 256
#define NG 64
#define NSLICE 4   // 64-dim output slices
#define NQ 4       // batch quarters
#define BLOCK 256
#define ST 8       // sample tile staged in LDS
#define MAXLIST 1024
#define SEG 68     // 64 data floats + 4 pad per K-segment (2-way banks = free)
#define PSTR 6     // partials stride per dd (4 used + 2 pad; keeps 8B align, 2-way banks)

// Block (g, slice, quarter). Thread t: dd=t>>3 (0..31), q=t&7. Owns dims
// (d0,d1)=(slice*64+dd, +32), K-range q*32..+31; A slice register-resident.
// Reduction: quad_perm DPP adds (VALU, no DS latency) fold q-groups of 4;
// lanes q=0,4 write 2 partials/output to LDS; phase B re-maps threads so
// stores are 64-consecutive-dim coalesced rows.

template <int CTRL>
__device__ __forceinline__ float qperm_add(float x) {
    // x + quad_perm(x): CTRL=0xB1 is lane-xor-1, 0x4E is lane-xor-2 (in quads)
    int xi = __float_as_int(x);
    int yi = __builtin_amdgcn_update_dpp(xi, xi, CTRL, 0xF, 0xF, true);
    return x + __int_as_float(yi);
}

__global__ __launch_bounds__(BLOCK, 4) void fused_kernel(
    const float* __restrict__ mu, const float* __restrict__ A,
    const float* __restrict__ eps, const int* __restrict__ k,
    float* __restrict__ out, int batch) {

    const int g     = blockIdx.x >> 4;
    const int slice = (blockIdx.x >> 2) & (NSLICE - 1);
    const int quart = blockIdx.x & (NQ - 1);
    const int t  = threadIdx.x;
    const int dd = t >> 3;   // 0..31
    const int q  = t & 7;    // 0..7
    const int d0 = slice * 64 + dd;
    const int d1 = d0 + 32;

    __shared__ int   list[MAXLIST];
    __shared__ int   lcount;
    __shared__ int   bidx_s[ST];
    __shared__ float eps_s[ST][4 * SEG];
    __shared__ float part[ST * 32 * PSTR];   // [s][dd][h*2+j], PSTR-padded

    if (t == 0) lcount = 0;
    __syncthreads();

    // ---- scan this quarter of k: one int4 per thread ----
    {
        const int qn = batch / NQ;            // 1024
        const int qb = quart * qn;
        int4 kv = ((const int4*)(k + qb))[t];
        int b0 = qb + t * 4;
        if (kv.x == g) list[atomicAdd(&lcount, 1)] = b0;
        if (kv.y == g) list[atomicAdd(&lcount, 1)] = b0 + 1;
        if (kv.z == g) list[atomicAdd(&lcount, 1)] = b0 + 2;
        if (kv.w == g) list[atomicAdd(&lcount, 1)] = b0 + 3;
    }

    // ---- A slices into registers (overlaps the scan) ----
    float4 a0[8], a1[8];
    {
        const float4* A0 = (const float4*)(A + ((size_t)g * DIM + d0) * DIM + q * 32);
        const float4* A1 = (const float4*)(A + ((size_t)g * DIM + d1) * DIM + q * 32);
#pragma unroll
        for (int i = 0; i < 8; ++i) { a0[i] = A0[i]; a1[i] = A1[i]; }
    }
    // mu in phase-B indexing: this thread stores dim (t&63) of samples
    const float mu_b = mu[g * DIM + slice * 64 + (t & 63)];

    __syncthreads();
    const int n = lcount;
    if (n == 0) return;  // uniform per block: barrier-safe

    // staging role: thread stages float4 `w` of rows s0 and s0+4
    const int s0 = t >> 6, w = t & 63;
    const int seg = w >> 4, within = (w & 15) * 4;
    const float4* eps4 = (const float4*)eps;

    float4 pf0, pf1;
    {
        int bA = list[min(s0, n - 1)];
        int bB = list[min(s0 + 4, n - 1)];
        pf0 = eps4[(size_t)bA * 64 + w];
        pf1 = eps4[(size_t)bB * 64 + w];
    }

    for (int t0 = 0; t0 < n; t0 += ST) {
        const int ns = min(ST, n - t0);
        __syncthreads();  // prev tile's eps/part reads complete
        *(float4*)(&eps_s[s0][seg * SEG + within])     = pf0;
        *(float4*)(&eps_s[s0 + 4][seg * SEG + within]) = pf1;
        if (t < ST) bidx_s[t] = list[min(t0 + t, n - 1)];
        __syncthreads();

        // prefetch next tile; loads stay in flight across compute
        if (t0 + ST < n) {
            int bA = list[min(t0 + ST + s0, n - 1)];
            int bB = list[min(t0 + ST + s0 + 4, n - 1)];
            pf0 = eps4[(size_t)bA * 64 + w];
            pf1 = eps4[(size_t)bB * 64 + w];
        }

        // ---- compute: 8 samples, fully unrolled, no cross-lane DS ----
        float acc0[ST], acc1[ST];
#pragma unroll
        for (int s = 0; s < ST; ++s) {
            const float* ep = &eps_s[s][(q >> 1) * SEG + (q & 1) * 32];
            float c0 = 0.f, c1 = 0.f;
#pragma unroll
            for (int i = 0; i < 8; ++i) {
                float4 e = *(const float4*)(ep + i * 4);
                c0 += a0[i].x * e.x + a0[i].y * e.y + a0[i].z * e.z + a0[i].w * e.w;
                c1 += a1[i].x * e.x + a1[i].y * e.y + a1[i].z * e.z + a1[i].w * e.w;
            }
            // fold q-groups of 4 via quad_perm DPP (VALU only)
            c0 = qperm_add<0xB1>(c0);
            c0 = qperm_add<0x4E>(c0);
            c1 = qperm_add<0xB1>(c1);
            c1 = qperm_add<0x4E>(c1);
            acc0[s] = c0;
            acc1[s] = c1;
        }
        if ((q & 3) == 0) {
            const int j = q >> 2;  // 0: K[0..127], 1: K[128..255]
#pragma unroll
            for (int s = 0; s < ST; ++s) {
                part[s * 32 * PSTR + dd * PSTR + 0 + j] = acc0[s];
                part[s * 32 * PSTR + dd * PSTR + 2 + j] = acc1[s];
            }
        }
        __syncthreads();

        // ---- phase B: coalesced epilogue ----
        {
            const int dim = t & 63;
            const int h = dim >> 5, ddm = dim & 31;
#pragma unroll
            for (int r = 0; r < 2; ++r) {
                int s = (t >> 6) + r * 4;
                if (s < ns) {
                    const float2 p =
                        *(const float2*)&part[s * 32 * PSTR + ddm * PSTR + h * 2];
                    out[(size_t)bidx_s[s] * DIM + slice * 64 + dim] =
                        p.x + p.y + mu_b;
                }
            }
        }
    }
}

extern "C" void kernel_launch(void* const* d_in, const int* in_sizes, int n_in,
                              void* d_out, int out_size, void* d_ws,
                              size_t ws_size, hipStream_t stream) {
    const float* mu  = (const float*)d_in[0];   // [NG, DIM]
    const float* A   = (const float*)d_in[1];   // [NG, DIM, DIM]
    const float* eps = (const float*)d_in[2];   // [B, DIM]
    const int*   k   = (const int*)d_in[3];     // [B] int32
    const int batch  = in_sizes[3];
    float* out = (float*)d_out;

    fused_kernel<<<NG * NSLICE * NQ, BLOCK, 0, stream>>>(mu, A, eps, k,
                                                         out, batch);
}

// Round 6
// 80.274 us; speedup vs baseline: 1.2154x; 1.2154x over previous
//
#include <hip/hip_runtime.h>
#include <hip/hip_bf16.h>

#define DIM 256
#define NG 64
#define BLOCK 256
#define NMAX 128     // samples per MFMA chunk (bucket n_g ~ 64 +/- 8)
#define LISTCAP 256
#define LSTR 65      // 64 fragment slots + 1 pad (short8 units) per (tile,kstep) row

typedef __attribute__((ext_vector_type(8))) short short8;   // 8 bf16 = 4 VGPRs
typedef __attribute__((ext_vector_type(4))) float floatx4;

__device__ __forceinline__ short f2bf(float f) {
    union { __hip_bfloat16 h; short s; } u;
    u.h = __float2bfloat16(f);
    return u.s;
}

__device__ __forceinline__ short8 pack8(float4 a, float4 b) {
    short8 r;
    r[0] = f2bf(a.x); r[1] = f2bf(a.y); r[2] = f2bf(a.z); r[3] = f2bf(a.w);
    r[4] = f2bf(b.x); r[5] = f2bf(b.y); r[6] = f2bf(b.z); r[7] = f2bf(b.w);
    return r;
}

// Block (g = bid>>2, mslice = bid&3): C[64 x n_g] = A[g][mslice*64..+64) x eps_g^T,
// out[b][m] = C + mu. Per-wave M-tile of 16; K=256 in 8 steps of 32.
// LDS holds A/B in packed MFMA-fragment order: slot (tile,kstep)*LSTR + lane,
// 16 B per lane -> ds_read_b128, lane-sequential, conflict-free.
__global__ __launch_bounds__(BLOCK, 1) void mfma_kernel(
    const float* __restrict__ mu, const float* __restrict__ A,
    const float* __restrict__ eps, const int* __restrict__ k,
    float* __restrict__ out, int batch) {

    const int g      = blockIdx.x >> 2;
    const int mslice = blockIdx.x & 3;
    const int t = threadIdx.x;
    const int l = t & 63;        // lane
    const int w = t >> 6;        // wave = M-tile
    const int quad = l >> 4;

    __shared__ short8 A_s[4 * 8 * LSTR];   // [mtile][kstep][lane]
    __shared__ short8 B_s[8 * 8 * LSTR];   // [ntile][kstep][lane]
    __shared__ int list[LISTCAP];
    __shared__ int lcount;

    // ---- issue A-slice loads early (64 floats/thread, k-contiguous) ----
    const int am = t >> 2;             // row 0..63 within slice
    const int ak0 = (t & 3) * 64;      // k base
    float4 av[16];
    {
        const float4* Ap = (const float4*)(A +
            ((size_t)(g * DIM + mslice * 64 + am)) * DIM + ak0);
#pragma unroll
        for (int i = 0; i < 16; ++i) av[i] = Ap[i];
    }
    // mu for this lane's 4 output rows (C/D layout: row = quad*4 + reg)
    const float4 muq = *(const float4*)(mu + g * DIM + mslice * 64 + w * 16 + quad * 4);

    if (t == 0) lcount = 0;
    __syncthreads();

    // ---- scan k (4096): build bucket list in LDS ----
#pragma unroll
    for (int rr = 0; rr < 4; ++rr) {
        int idx = t + rr * BLOCK;
        int4 kv = ((const int4*)k)[idx];
        int b0 = idx * 4;
        if (kv.x == g) { int p = atomicAdd(&lcount, 1); if (p < LISTCAP) list[p] = b0; }
        if (kv.y == g) { int p = atomicAdd(&lcount, 1); if (p < LISTCAP) list[p] = b0 + 1; }
        if (kv.z == g) { int p = atomicAdd(&lcount, 1); if (p < LISTCAP) list[p] = b0 + 2; }
        if (kv.w == g) { int p = atomicAdd(&lcount, 1); if (p < LISTCAP) list[p] = b0 + 3; }
    }

    // ---- convert + write A fragments ----
    // chunk cc: k = ak0 + cc*8 -> kstep=k>>5, quad=(k>>3)&3, fraglane=quad*16+(am&15)
    {
        const int mtile = am >> 4;     // == w
        const int mlo = am & 15;
#pragma unroll
        for (int cc = 0; cc < 8; ++cc) {
            int kk = ak0 + cc * 8;
            int ks = kk >> 5;
            int qd = (kk >> 3) & 3;
            A_s[(mtile * 8 + ks) * LSTR + qd * 16 + mlo] =
                pack8(av[cc * 2], av[cc * 2 + 1]);
        }
    }
    __syncthreads();

    const int n = min(lcount, LISTCAP);
    if (n == 0) return;  // block-uniform

    for (int c0 = 0; c0 < n; c0 += NMAX) {
        const int nc = min(NMAX, n - c0);
        if (c0) __syncthreads();  // prior chunk's B reads complete

        // ---- stage B fragments: rounds of 16 samples, 16 threads/sample ----
        {
            const int sloc = t >> 4;   // sample slot within round (0..15)
            const int j16  = t & 15;   // 16-float k-chunk
            const int nround = (nc + 15) >> 4;
            for (int r = 0; r < nround; ++r) {
                int s = r * 16 + sloc;
                int b = list[c0 + min(s, nc - 1)];   // clamp: dup-stage, cols guarded
                const float4* ep = (const float4*)(eps + (size_t)b * DIM + j16 * 16);
                float4 e0 = ep[0], e1 = ep[1], e2 = ep[2], e3 = ep[3];
                int ks = j16 >> 1;
                int q0 = (2 * j16) & 3, q1 = (2 * j16 + 1) & 3;
                B_s[(r * 8 + ks) * LSTR + q0 * 16 + sloc] = pack8(e0, e1);
                B_s[(r * 8 + ks) * LSTR + q1 * 16 + sloc] = pack8(e2, e3);
            }
        }
        __syncthreads();

        // ---- MFMA: wave w = M-tile; loop N-tiles ----
        const int ntiles = (nc + 15) >> 4;
        for (int nt = 0; nt < ntiles; ++nt) {
            floatx4 acc = {0.f, 0.f, 0.f, 0.f};
#pragma unroll
            for (int ks = 0; ks < 8; ++ks) {
                short8 af = A_s[(w * 8 + ks) * LSTR + l];
                short8 bf = B_s[(nt * 8 + ks) * LSTR + l];
                acc = __builtin_amdgcn_mfma_f32_16x16x32_bf16(af, bf, acc, 0, 0, 0);
            }
            int col = l & 15;
            int s = nt * 16 + col;
            if (s < nc) {
                int b = list[c0 + s];
                float4 ov;
                ov.x = acc[0] + muq.x;
                ov.y = acc[1] + muq.y;
                ov.z = acc[2] + muq.z;
                ov.w = acc[3] + muq.w;
                *(float4*)(out + (size_t)b * DIM + mslice * 64 + w * 16 + quad * 4) = ov;
            }
        }
    }
}

extern "C" void kernel_launch(void* const* d_in, const int* in_sizes, int n_in,
                              void* d_out, int out_size, void* d_ws,
                              size_t ws_size, hipStream_t stream) {
    const float* mu  = (const float*)d_in[0];   // [NG, DIM]
    const float* A   = (const float*)d_in[1];   // [NG, DIM, DIM]
    const float* eps = (const float*)d_in[2];   // [B, DIM]
    const int*   k   = (const int*)d_in[3];     // [B] int32
    const int batch  = in_sizes[3];
    float* out = (float*)d_out;

    mfma_kernel<<<NG * 4, BLOCK, 0, stream>>>(mu, A, eps, k, out, batch);
}